// Round 5
// baseline (200.188 us; speedup 1.0000x reference)
//
#include <hip/hip_runtime.h>

#define DEV __device__ __forceinline__

// ---------------------------------------------------------------------------
// R5: lazy-CNOT (GF2 basis tracking) + real-valued encode.
// Layout: 4 batch elements per wave (grp = lane>>4), 16 lanes/element,
// 16 amps/lane. Stored index j = (sub<<4)|s, sub = lane&15.
// Qubit -> j-bit assignment: q0,q2,q4,q6 -> lane bits 3,2,1,0 (masks 8,4,2,1);
//                            q1,q3,q5,q7 -> s bits 3,2,1,0    (masks 8,4,2,1).
// All CNOTs are folded into per-gate XOR pair-masks (LM = lane part, SM = s
// part) and parity masks (LR, SR) giving the qubit value b = par(lane&LR) ^
// par(s&SR). Masks precomputed by evolving A (rows) / A^-1 (cols) through the
// 4 encode CNOT-ring cycles. Encode state is purely real (RY only).
// ---------------------------------------------------------------------------

DEV int lpar(int lane, int m) { return __builtin_popcount(lane & m) & 1; }
constexpr int cpar(int v) { return (v ^ (v >> 1) ^ (v >> 2) ^ (v >> 3)) & 1; }

// ---- real RY with general pair mask / parity ------------------------------
template<int LM, int SM, int LR, int SR>
DEV void ryr(float* p, float gc, float gs, int lane) {
  const float sg0 = lpar(lane, LR) ? gs : -gs;   // sign when cpar(s&SR)==0
  const float sg1 = -sg0;
  if constexpr (LM != 0) {
    float t[16];
    #pragma unroll
    for (int s = 0; s < 16; ++s) t[s] = __shfl_xor(p[s ^ SM], LM);
    #pragma unroll
    for (int s = 0; s < 16; ++s)
      p[s] = gc * p[s] + (cpar(s & SR) ? sg1 : sg0) * t[s];
  } else {
    constexpr int LOW = SM & (-SM);
    #pragma unroll
    for (int s = 0; s < 16; ++s) if (!(s & LOW)) {
      const int s1 = s ^ SM;
      float a = p[s], b = p[s1];
      float sg = cpar(s & SR) ? sg1 : sg0;
      p[s]  = gc * a + sg * b;
      p[s1] = gc * b - sg * a;
    }
  }
}

// ---- complex U3: u[8] = {u00r,u00i,u01r,u01i,u10r,u10i,u11r,u11i} --------
// new[j] = u[b][b]*a[j] + u[b][1-b]*a[j^m],  b = par(lane&LR)^cpar(s&SR)
template<int LM, int SM, int LR, int SR>
DEV void u3_g(float* pr, float* pi, const float* u, int lane) {
  const bool hl = lpar(lane, LR);
  // class cpar==0 -> b = hl ; class cpar==1 -> b = !hl
  const float d0r = hl ? u[6] : u[0], d0i = hl ? u[7] : u[1];
  const float o0r = hl ? u[4] : u[2], o0i = hl ? u[5] : u[3];
  const float d1r = hl ? u[0] : u[6], d1i = hl ? u[1] : u[7];
  const float o1r = hl ? u[2] : u[4], o1i = hl ? u[3] : u[5];
  if constexpr (LM != 0) {
    float tr[16], ti[16];
    #pragma unroll
    for (int s = 0; s < 16; ++s) {
      tr[s] = __shfl_xor(pr[s ^ SM], LM);
      ti[s] = __shfl_xor(pi[s ^ SM], LM);
    }
    #pragma unroll
    for (int s = 0; s < 16; ++s) {
      const bool c1 = cpar(s & SR);
      const float dr = c1 ? d1r : d0r, di = c1 ? d1i : d0i;
      const float orr = c1 ? o1r : o0r, oi = c1 ? o1i : o0i;
      float ar = pr[s], ai = pi[s];
      pr[s] = dr*ar - di*ai + orr*tr[s] - oi*ti[s];
      pi[s] = dr*ai + di*ar + orr*ti[s] + oi*tr[s];
    }
  } else {
    constexpr int LOW = SM & (-SM);
    #pragma unroll
    for (int s = 0; s < 16; ++s) if (!(s & LOW)) {
      const int s1 = s ^ SM;
      const bool c1 = cpar(s & SR);           // class of amp s; s1 is opposite
      const float dAr = c1 ? d1r : d0r, dAi = c1 ? d1i : d0i;
      const float oAr = c1 ? o1r : o0r, oAi = c1 ? o1i : o0i;
      const float dBr = c1 ? d0r : d1r, dBi = c1 ? d0i : d1i;
      const float oBr = c1 ? o0r : o1r, oBi = c1 ? o0i : o1i;
      float ar = pr[s], ai = pi[s], br = pr[s1], bi = pi[s1];
      pr[s]  = dAr*ar - dAi*ai + oAr*br - oAi*bi;
      pi[s]  = dAr*ai + dAi*ar + oAr*bi + oAi*br;
      pr[s1] = dBr*br - dBi*bi + oBr*ar - oBi*ai;
      pi[s1] = dBr*bi + dBi*br + oBr*ai + oBi*ar;
    }
  }
}

// ---- CRX: control parity (LRc,SRc), target pair mask (LMt,SMt) -----------
template<int LMt, int SMt, int LRc, int SRc>
DEV void crx_g(float* pr, float* pi, float c, float s_, int lane) {
  const bool hl = lpar(lane, LRc);
  const float cc0 = hl ? c : 1.0f, ss0 = hl ? s_ : 0.0f;   // class cpar==0
  const float cc1 = hl ? 1.0f : c, ss1 = hl ? 0.0f : s_;   // class cpar==1
  if constexpr (LMt != 0) {
    float tr[16], ti[16];
    #pragma unroll
    for (int s = 0; s < 16; ++s) {
      tr[s] = __shfl_xor(pr[s ^ SMt], LMt);
      ti[s] = __shfl_xor(pi[s ^ SMt], LMt);
    }
    #pragma unroll
    for (int s = 0; s < 16; ++s) {
      const bool c1 = cpar(s & SRc);
      const float cc = c1 ? cc1 : cc0, ss = c1 ? ss1 : ss0;
      float ar = pr[s], ai = pi[s];
      pr[s] = cc * ar + ss * ti[s];
      pi[s] = cc * ai - ss * tr[s];
    }
  } else {
    constexpr int LOW = SMt & (-SMt);
    #pragma unroll
    for (int s = 0; s < 16; ++s) if (!(s & LOW)) {
      const int s1 = s ^ SMt;                  // same control value (<rc,mt>=0)
      const bool c1 = cpar(s & SRc);
      const float cc = c1 ? cc1 : cc0, ss = c1 ? ss1 : ss0;
      float ar = pr[s], ai = pi[s], br = pr[s1], bi = pi[s1];
      pr[s]  = cc * ar + ss * bi;
      pi[s]  = cc * ai - ss * br;
      pr[s1] = cc * br + ss * ai;
      pi[s1] = cc * bi - ss * ar;
    }
  }
}

// ---- U4 (fused entangler), 2-gather decomposition -------------------------
// final[j] = pA[j] + pB[j^mc];  pA = W[r,r]a + W[r,r^1]t;  pB = W[r^2,r]a +
// W[r^2,r^1]t;  t = a[.^mt];  r = R ^ q(s), R = 2*par(lane&LRc)+par(lane&LRt),
// q(s) = 2*cpar(s&SRc)+cpar(s&SRt).  w2 = 16 complex entries, row-major.
#define U4CLASS(Q)                                                            \
  if constexpr (!(((SRc == 0) && (Q & 2)) || ((SRt == 0) && (Q & 1)))) {      \
    const int r1 = R ^ Q, r2 = r1 ^ 2;                                        \
    const float2 wd = w2[r1 * 4 + r1],       wo = w2[r1 * 4 + (r1 ^ 1)];      \
    const float2 vd = w2[r2 * 4 + r1],       vo = w2[r2 * 4 + (r1 ^ 1)];      \
    _Pragma("unroll")                                                         \
    for (int s = 0; s < 16; ++s)                                              \
      if (((cpar(s & SRc) << 1) | cpar(s & SRt)) == Q) {                      \
        float ar = pr[s], ai = pi[s], br = tr[s], bi = ti[s];                 \
        pr[s] = wd.x*ar - wd.y*ai + wo.x*br - wo.y*bi;                        \
        pi[s] = wd.x*ai + wd.y*ar + wo.x*bi + wo.y*br;                        \
        tr[s] = vd.x*ar - vd.y*ai + vo.x*br - vo.y*bi;                        \
        ti[s] = vd.x*ai + vd.y*ar + vo.x*bi + vo.y*br;                        \
      }                                                                       \
  }

template<int LMc, int SMc, int LMt, int SMt, int LRc, int SRc, int LRt, int SRt>
DEV void u4_g(float* pr, float* pi, const float2* w2, int lane) {
  const int R = (lpar(lane, LRc) << 1) | lpar(lane, LRt);
  float tr[16], ti[16];
  #pragma unroll
  for (int s = 0; s < 16; ++s) {
    float vr = pr[s ^ SMt], vi = pi[s ^ SMt];
    if constexpr (LMt != 0) { vr = __shfl_xor(vr, LMt); vi = __shfl_xor(vi, LMt); }
    tr[s] = vr; ti[s] = vi;
  }
  U4CLASS(0) U4CLASS(1) U4CLASS(2) U4CLASS(3)
  #pragma unroll
  for (int s = 0; s < 16; ++s) {
    float br = tr[s ^ SMc], bi = ti[s ^ SMc];
    if constexpr (LMc != 0) { br = __shfl_xor(br, LMc); bi = __shfl_xor(bi, LMc); }
    pr[s] += br; pi[s] += bi;
  }
}

// ---- U3 coefficient build -------------------------------------------------
DEV void u3_make(float t, float p, float l, float* u) {
  float c = __cosf(0.5f * t), s = __sinf(0.5f * t);
  float cp = __cosf(p), sp = __sinf(p);
  float cl = __cosf(l), sl = __sinf(l);
  float cpl = __cosf(p + l), spl = __sinf(p + l);
  u[0] = c;        u[1] = 0.0f;
  u[2] = -cl * s;  u[3] = -sl * s;
  u[4] = cp * s;   u[5] = sp * s;
  u[6] = cpl * c;  u[7] = spl * c;
}

// ---- <Z3>,<Z7>: r3 = (LR=10,SR=1), r7 = (LR=10,SR=0) ----------------------
DEV void expz_fin(const float* pr, const float* pi, int lane, float& z3, float& z7) {
  float t3 = 0.0f, t7 = 0.0f;
  #pragma unroll
  for (int s = 0; s < 16; ++s) {
    float p = pr[s] * pr[s] + pi[s] * pi[s];
    t7 += p;
    t3 += (s & 1) ? -p : p;
  }
  if (lpar(lane, 10)) { t3 = -t3; t7 = -t7; }
  #pragma unroll
  for (int m = 1; m < 16; m <<= 1) {
    t3 += __shfl_xor(t3, m);
    t7 += __shfl_xor(t7, m);
  }
  z3 = t3; z7 = t7;
}

// ---------------------------------------------------------------------------

__global__ __launch_bounds__(256, 4)
void qcnn_kernel(const float* __restrict__ x,
                 const float* __restrict__ rz_p, const float* __restrict__ ry_p,
                 const float* __restrict__ ry2_p, const float* __restrict__ crx_p,
                 const float* __restrict__ u3_p, const float* __restrict__ u3b_p,
                 const float* __restrict__ W1, const float* __restrict__ b1,
                 const float* __restrict__ W2, const float* __restrict__ b2,
                 float* __restrict__ out, int B) {
  __shared__ __align__(8) float cw[64];   // 2 layers x 16 complex fused-U4

  const int tid  = threadIdx.x;
  const int lane = tid & 63;
  const int wave = tid >> 6;
  const int grp  = lane >> 4;
  const int sub  = lane & 15;
  const int gb   = lane & 48;
  const int elem = blockIdx.x * 16 + wave * 4 + grp;
  const int elemc = elem < B ? elem : (B - 1);

  // ---- fused U4 build (wave 0, lanes 0..31; one complex entry per lane) ---
  if (tid < 32) {
    const int lay = tid >> 4, e = tid & 15, i4 = e >> 2, j4 = e & 3;
    const int base = tid & 48;
    const float c45 = 0.70710678118654752f;
    float rz = rz_p[lay], ry = ry_p[lay], ry2 = ry2_p[lay];
    float mr = (i4 == j4) ? c45 : 0.0f;
    float mi = (i4 == j4) ? ((i4 & 1) ? -c45 : c45) : 0.0f;
    { int t = (i4 & 1) ? (i4 ^ 2) : i4; int src = base | (t << 2) | j4;
      mr = __shfl(mr, src); mi = __shfl(mi, src); }
    { float cz = __cosf(0.5f * rz), sz = __sinf(0.5f * rz);
      float di = (i4 & 2) ? sz : -sz;
      float nr = cz * mr - di * mi, ni = cz * mi + di * mr; mr = nr; mi = ni; }
    { float cy = __cosf(0.5f * ry), sy = __sinf(0.5f * ry);
      int src = base | ((i4 ^ 1) << 2) | j4;
      float orr = __shfl(mr, src), oii = __shfl(mi, src);
      float sg = (i4 & 1) ? sy : -sy;
      mr = cy * mr + sg * orr; mi = cy * mi + sg * oii; }
    { int t = (i4 & 2) ? (i4 ^ 1) : i4; int src = base | (t << 2) | j4;
      mr = __shfl(mr, src); mi = __shfl(mi, src); }
    { float cy = __cosf(0.5f * ry2), sy = __sinf(0.5f * ry2);
      int src = base | ((i4 ^ 1) << 2) | j4;
      float orr = __shfl(mr, src), oii = __shfl(mi, src);
      float sg = (i4 & 1) ? sy : -sy;
      mr = cy * mr + sg * orr; mi = cy * mi + sg * oii; }
    { int t = (i4 & 1) ? (i4 ^ 2) : i4; int src = base | (t << 2) | j4;
      mr = __shfl(mr, src); mi = __shfl(mi, src); }
    { float di = (i4 & 2) ? c45 : -c45;
      float nr = c45 * mr - di * mi, ni = c45 * mi + di * mr; mr = nr; mi = ni; }
    cw[(lay * 16 + e) * 2]     = mr;
    cw[(lay * 16 + e) * 2 + 1] = mi;
  }

  // ---- angles: lane sub holds angles 2*sub, 2*sub+1 -----------------------
  float2 aa = ((const float2*)x)[(size_t)elemc * 16 + sub];
  float ch0 = __cosf(0.5f * aa.x), sh0 = __sinf(0.5f * aa.x);
  float ch1 = __cosf(0.5f * aa.y), sh1 = __sinf(0.5f * aa.y);

  // broadcast cos/sin of all 8 cycle-1 angles
  float cq[8], sq[8];
  #pragma unroll
  for (int q = 0; q < 8; ++q) {
    cq[q] = __shfl((q & 1) ? ch1 : ch0, gb | (q >> 1));
    sq[q] = __shfl((q & 1) ? sh1 : sh0, gb | (q >> 1));
  }

  // ---- product-state init (replaces cycle-1 RYs; state real) --------------
  float p[16];
  {
    float g = ((sub & 8) ? sq[0] : cq[0]) * ((sub & 4) ? sq[2] : cq[2]) *
              ((sub & 2) ? sq[4] : cq[4]) * ((sub & 1) ? sq[6] : cq[6]);
    float h13[4] = {cq[1]*cq[3], cq[1]*sq[3], sq[1]*cq[3], sq[1]*sq[3]};
    float h57[4] = {cq[5]*cq[7], cq[5]*sq[7], sq[5]*cq[7], sq[5]*sq[7]};
    #pragma unroll
    for (int i = 0; i < 4; ++i) h13[i] *= g;
    #pragma unroll
    for (int s = 0; s < 16; ++s) p[s] = h13[s >> 2] * h57[s & 3];
  }

  // ---- encode cycles 2..4 (24 real RYs, CNOTs folded into masks) ----------
  #define ENC(k, LM, SM, LR, SR) {                                  \
    float gc = __shfl(((k) & 1) ? ch1 : ch0, gb | ((k) >> 1));      \
    float gs = __shfl(((k) & 1) ? sh1 : sh0, gb | ((k) >> 1));      \
    ryr<LM, SM, LR, SR>(p, gc, gs, lane); }

  ENC(8,  8,8, 7,15)  ENC(9,  4,8, 8,8)   ENC(10, 4,4, 12,8)  ENC(11, 2,4, 12,12)
  ENC(12, 2,2, 14,12) ENC(13, 1,2, 14,14) ENC(14, 1,1, 15,14) ENC(15, 8,9, 15,15)
  ENC(16, 12,0, 8,15) ENC(17, 0,12, 15,7) ENC(18, 6,0, 3,15)  ENC(19, 0,6, 15,3)
  ENC(20, 3,0, 1,15)  ENC(21, 0,3, 15,1)  ENC(22, 9,8, 0,15)  ENC(23, 4,9, 15,0)
  ENC(24, 12,12, 2,10) ENC(25, 6,12, 7,8) ENC(26, 6,6, 4,7)   ENC(27, 3,6, 11,4)
  ENC(28, 3,3, 10,11)  ENC(29, 9,11, 5,10) ENC(30, 13,1, 5,5) ENC(31, 8,5, 10,5)
  #undef ENC

  // park real encode state for psi1
  float enc[16];
  #pragma unroll
  for (int s = 0; s < 16; ++s) enc[s] = p[s];

  __syncthreads();  // cw ready
  const float2* w0 = (const float2*)cw;
  const float2* w1 = ((const float2*)cw) + 16;

  // ---- psi0: conv layers (final masks: m0(10,0) m1(0,10) m2(5,0) m3(0,5)
  //     m4(10,8) m5(4,10) m6(5,4) m7(2,5); r0(8,10) r1(5,2) r2(1,5) r3(10,1)
  //     r4(0,10) r5(5,0) r6(0,5) r7(10,0)) --------------------------------
  float pi_[16];
  #pragma unroll
  for (int s = 0; s < 16; ++s) pi_[s] = 0.0f;

  u4_g<10,0,  0,10, 8,10, 5,2 >(p, pi_, w0, lane);   // (0,1)
  u4_g<5,0,   0,5,  1,5,  10,1>(p, pi_, w0, lane);   // (2,3)
  u4_g<10,8,  4,10, 0,10, 5,0 >(p, pi_, w0, lane);   // (4,5)
  u4_g<5,4,   2,5,  0,5,  10,0>(p, pi_, w0, lane);   // (6,7)
  u4_g<0,10,  5,0,  5,2,  1,5 >(p, pi_, w0, lane);   // (1,2)
  u4_g<0,5,   10,8, 10,1, 0,10>(p, pi_, w0, lane);   // (3,4)
  u4_g<4,10,  5,4,  5,0,  0,5 >(p, pi_, w0, lane);   // (5,6)
  {
    float ua[8]; u3_make(u3_p[0], u3_p[1], u3_p[2], ua);
    u3_g<0,10, 5,2 >(p, pi_, ua, lane);   // q1
    u3_g<0,5,  10,1>(p, pi_, ua, lane);   // q3
    u3_g<4,10, 5,0 >(p, pi_, ua, lane);   // q5
    u3_g<2,5,  10,0>(p, pi_, ua, lane);   // q7
  }
  u4_g<0,10,  0,5,  5,2,  10,1>(p, pi_, w1, lane);   // (1,3)
  u4_g<4,10,  2,5,  5,0,  10,0>(p, pi_, w1, lane);   // (5,7)
  u4_g<0,5,   4,10, 10,1, 5,0 >(p, pi_, w1, lane);   // (3,5)
  {
    float ua[8]; u3_make(u3_p[3], u3_p[4], u3_p[5], ua);
    u3_g<0,5,  10,1>(p, pi_, ua, lane);   // q3
    u3_g<2,5,  10,0>(p, pi_, ua, lane);   // q7
  }

  float f0, f1;
  expz_fin(p, pi_, lane, f0, f1);

  // ---- psi1: CRX ladders + U3b -------------------------------------------
  #pragma unroll
  for (int s = 0; s < 16; ++s) { p[s] = enc[s]; pi_[s] = 0.0f; }

  {
    float t = crx_p[0];
    float cc = __cosf(0.5f * t), ss = __sinf(0.5f * t);
    crx_g<0,10, 8,10>(p, pi_, cc, ss, lane);   // (0,1)
    crx_g<0,5,  1,5 >(p, pi_, cc, ss, lane);   // (2,3)
    crx_g<4,10, 0,10>(p, pi_, cc, ss, lane);   // (4,5)
    crx_g<2,5,  0,5 >(p, pi_, cc, ss, lane);   // (6,7)
    crx_g<5,0,  5,2 >(p, pi_, cc, ss, lane);   // (1,2)
    crx_g<10,8, 10,1>(p, pi_, cc, ss, lane);   // (3,4)
    crx_g<5,4,  5,0 >(p, pi_, cc, ss, lane);   // (5,6)
  }
  {
    float ub[8]; u3_make(u3b_p[0], u3b_p[1], u3b_p[2], ub);
    u3_g<0,10, 5,2 >(p, pi_, ub, lane);
    u3_g<0,5,  10,1>(p, pi_, ub, lane);
    u3_g<4,10, 5,0 >(p, pi_, ub, lane);
    u3_g<2,5,  10,0>(p, pi_, ub, lane);
  }
  {
    float t = crx_p[1];
    float cc = __cosf(0.5f * t), ss = __sinf(0.5f * t);
    crx_g<0,5,  5,2 >(p, pi_, cc, ss, lane);   // (1,3)
    crx_g<2,5,  5,0 >(p, pi_, cc, ss, lane);   // (5,7)
    crx_g<4,10, 10,1>(p, pi_, cc, ss, lane);   // (3,5)
  }
  {
    float ub[8]; u3_make(u3b_p[3], u3b_p[4], u3b_p[5], ub);
    u3_g<0,5,  10,1>(p, pi_, ub, lane);
    u3_g<2,5,  10,0>(p, pi_, ub, lane);
  }

  float f2, f3;
  expz_fin(p, pi_, lane, f2, f3);

  // ---- MLP ----------------------------------------------------------------
  const int j = (sub < 15) ? sub : 0;
  float acc = W1[j * 4 + 0] * f0 + W1[j * 4 + 1] * f1 +
              W1[j * 4 + 2] * f2 + W1[j * 4 + 3] * f3 + b1[j];
  float e2 = __expf(2.0f * acc);
  float th = (e2 - 1.0f) / (e2 + 1.0f);
  float part = (sub < 15) ? th * W2[j] : 0.0f;
  #pragma unroll
  for (int m = 1; m < 16; m <<= 1) part += __shfl_xor(part, m);

  if (sub == 0 && elem < B) {
    float z = part + b2[0];
    out[elem] = 1.0f / (1.0f + __expf(-z));
  }
}

extern "C" void kernel_launch(void* const* d_in, const int* in_sizes, int n_in,
                              void* d_out, int out_size, void* d_ws, size_t ws_size,
                              hipStream_t stream) {
  (void)n_in; (void)out_size; (void)d_ws; (void)ws_size;
  const float* x     = (const float*)d_in[0];
  const float* rz_p  = (const float*)d_in[1];
  const float* ry_p  = (const float*)d_in[2];
  const float* ry2_p = (const float*)d_in[3];
  const float* crx_p = (const float*)d_in[4];
  const float* u3_p  = (const float*)d_in[5];
  const float* u3b_p = (const float*)d_in[6];
  const float* W1    = (const float*)d_in[7];
  const float* b1    = (const float*)d_in[8];
  const float* W2    = (const float*)d_in[9];
  const float* b2    = (const float*)d_in[10];
  float* out = (float*)d_out;

  const int B = in_sizes[0] / 32;          // 8192
  const int blocks = (B + 15) / 16;        // 4 elems/wave, 4 waves/block
  qcnn_kernel<<<dim3(blocks), dim3(256), 0, stream>>>(
      x, rz_p, ry_p, ry2_p, crx_p, u3_p, u3b_p, W1, b1, W2, b2, out, B);
}

// Round 6
// 114.793 us; speedup vs baseline: 1.7439x; 1.7439x over previous
//
#include <hip/hip_runtime.h>

#define DEV __device__ __forceinline__

// ---------------------------------------------------------------------------
// R6 = R5 (lazy-CNOT GF2 basis tracking + real-valued encode; correctness-
// verified in R5) with the spill fixes:
//   - __launch_bounds__(256, 2): 256-VGPR cap. (256,4) made LLVM pick a
//     64-reg allocation and spill 269 MB/dispatch (R5). (256,2) is the only
//     bound that has produced a sane allocation for a big live set (R1).
//   - enc (the parked copy of the encoded state for psi1) lives in LDS
//     during the psi0 conv phase: -16 VGPRs of peak pressure for 8 DS ops.
// Layout: 4 batch elements per wave (grp = lane>>4), 16 lanes/element,
// 16 amps/lane. Stored index j = (sub<<4)|s, sub = lane&15.
// Qubit -> j-bit: q0,q2,q4,q6 -> lane bits 3..0; q1,q3,q5,q7 -> s bits 3..0.
// All 32 encode CNOTs folded into per-gate XOR pair-masks (LM,SM) and parity
// masks (LR,SR); b = par(lane&LR) ^ par(s&SR). Encode state purely real.
// ---------------------------------------------------------------------------

DEV int lpar(int lane, int m) { return __builtin_popcount(lane & m) & 1; }
constexpr int cpar(int v) { return (v ^ (v >> 1) ^ (v >> 2) ^ (v >> 3)) & 1; }

// ---- real RY with general pair mask / parity ------------------------------
template<int LM, int SM, int LR, int SR>
DEV void ryr(float* p, float gc, float gs, int lane) {
  const float sg0 = lpar(lane, LR) ? gs : -gs;   // sign when cpar(s&SR)==0
  const float sg1 = -sg0;
  if constexpr (LM != 0) {
    float t[16];
    #pragma unroll
    for (int s = 0; s < 16; ++s) t[s] = __shfl_xor(p[s ^ SM], LM);
    #pragma unroll
    for (int s = 0; s < 16; ++s)
      p[s] = gc * p[s] + (cpar(s & SR) ? sg1 : sg0) * t[s];
  } else {
    constexpr int LOW = SM & (-SM);
    #pragma unroll
    for (int s = 0; s < 16; ++s) if (!(s & LOW)) {
      const int s1 = s ^ SM;
      float a = p[s], b = p[s1];
      float sg = cpar(s & SR) ? sg1 : sg0;
      p[s]  = gc * a + sg * b;
      p[s1] = gc * b - sg * a;
    }
  }
}

// ---- complex U3: u[8] = {u00r,u00i,u01r,u01i,u10r,u10i,u11r,u11i} --------
template<int LM, int SM, int LR, int SR>
DEV void u3_g(float* pr, float* pi, const float* u, int lane) {
  const bool hl = lpar(lane, LR);
  const float d0r = hl ? u[6] : u[0], d0i = hl ? u[7] : u[1];
  const float o0r = hl ? u[4] : u[2], o0i = hl ? u[5] : u[3];
  const float d1r = hl ? u[0] : u[6], d1i = hl ? u[1] : u[7];
  const float o1r = hl ? u[2] : u[4], o1i = hl ? u[3] : u[5];
  if constexpr (LM != 0) {
    float tr[16], ti[16];
    #pragma unroll
    for (int s = 0; s < 16; ++s) {
      tr[s] = __shfl_xor(pr[s ^ SM], LM);
      ti[s] = __shfl_xor(pi[s ^ SM], LM);
    }
    #pragma unroll
    for (int s = 0; s < 16; ++s) {
      const bool c1 = cpar(s & SR);
      const float dr = c1 ? d1r : d0r, di = c1 ? d1i : d0i;
      const float orr = c1 ? o1r : o0r, oi = c1 ? o1i : o0i;
      float ar = pr[s], ai = pi[s];
      pr[s] = dr*ar - di*ai + orr*tr[s] - oi*ti[s];
      pi[s] = dr*ai + di*ar + orr*ti[s] + oi*tr[s];
    }
  } else {
    constexpr int LOW = SM & (-SM);
    #pragma unroll
    for (int s = 0; s < 16; ++s) if (!(s & LOW)) {
      const int s1 = s ^ SM;
      const bool c1 = cpar(s & SR);
      const float dAr = c1 ? d1r : d0r, dAi = c1 ? d1i : d0i;
      const float oAr = c1 ? o1r : o0r, oAi = c1 ? o1i : o0i;
      const float dBr = c1 ? d0r : d1r, dBi = c1 ? d0i : d1i;
      const float oBr = c1 ? o0r : o1r, oBi = c1 ? o0i : o1i;
      float ar = pr[s], ai = pi[s], br = pr[s1], bi = pi[s1];
      pr[s]  = dAr*ar - dAi*ai + oAr*br - oAi*bi;
      pi[s]  = dAr*ai + dAi*ar + oAr*bi + oAi*br;
      pr[s1] = dBr*br - dBi*bi + oBr*ar - oBi*ai;
      pi[s1] = dBr*bi + dBi*br + oBr*ai + oBi*ar;
    }
  }
}

// ---- CRX: control parity (LRc,SRc), target pair mask (LMt,SMt) -----------
template<int LMt, int SMt, int LRc, int SRc>
DEV void crx_g(float* pr, float* pi, float c, float s_, int lane) {
  const bool hl = lpar(lane, LRc);
  const float cc0 = hl ? c : 1.0f, ss0 = hl ? s_ : 0.0f;
  const float cc1 = hl ? 1.0f : c, ss1 = hl ? 0.0f : s_;
  if constexpr (LMt != 0) {
    float tr[16], ti[16];
    #pragma unroll
    for (int s = 0; s < 16; ++s) {
      tr[s] = __shfl_xor(pr[s ^ SMt], LMt);
      ti[s] = __shfl_xor(pi[s ^ SMt], LMt);
    }
    #pragma unroll
    for (int s = 0; s < 16; ++s) {
      const bool c1 = cpar(s & SRc);
      const float cc = c1 ? cc1 : cc0, ss = c1 ? ss1 : ss0;
      float ar = pr[s], ai = pi[s];
      pr[s] = cc * ar + ss * ti[s];
      pi[s] = cc * ai - ss * tr[s];
    }
  } else {
    constexpr int LOW = SMt & (-SMt);
    #pragma unroll
    for (int s = 0; s < 16; ++s) if (!(s & LOW)) {
      const int s1 = s ^ SMt;
      const bool c1 = cpar(s & SRc);
      const float cc = c1 ? cc1 : cc0, ss = c1 ? ss1 : ss0;
      float ar = pr[s], ai = pi[s], br = pr[s1], bi = pi[s1];
      pr[s]  = cc * ar + ss * bi;
      pi[s]  = cc * ai - ss * br;
      pr[s1] = cc * br + ss * ai;
      pi[s1] = cc * bi - ss * ar;
    }
  }
}

// ---- U4 (fused entangler), 2-gather decomposition -------------------------
#define U4CLASS(Q)                                                            \
  if constexpr (!(((SRc == 0) && (Q & 2)) || ((SRt == 0) && (Q & 1)))) {      \
    const int r1 = R ^ Q, r2 = r1 ^ 2;                                        \
    const float2 wd = w2[r1 * 4 + r1],       wo = w2[r1 * 4 + (r1 ^ 1)];      \
    const float2 vd = w2[r2 * 4 + r1],       vo = w2[r2 * 4 + (r1 ^ 1)];      \
    _Pragma("unroll")                                                         \
    for (int s = 0; s < 16; ++s)                                              \
      if (((cpar(s & SRc) << 1) | cpar(s & SRt)) == Q) {                      \
        float ar = pr[s], ai = pi[s], br = tr[s], bi = ti[s];                 \
        pr[s] = wd.x*ar - wd.y*ai + wo.x*br - wo.y*bi;                        \
        pi[s] = wd.x*ai + wd.y*ar + wo.x*bi + wo.y*br;                        \
        tr[s] = vd.x*ar - vd.y*ai + vo.x*br - vo.y*bi;                        \
        ti[s] = vd.x*ai + vd.y*ar + vo.x*bi + vo.y*br;                        \
      }                                                                       \
  }

template<int LMc, int SMc, int LMt, int SMt, int LRc, int SRc, int LRt, int SRt>
DEV void u4_g(float* pr, float* pi, const float2* w2, int lane) {
  const int R = (lpar(lane, LRc) << 1) | lpar(lane, LRt);
  float tr[16], ti[16];
  #pragma unroll
  for (int s = 0; s < 16; ++s) {
    float vr = pr[s ^ SMt], vi = pi[s ^ SMt];
    if constexpr (LMt != 0) { vr = __shfl_xor(vr, LMt); vi = __shfl_xor(vi, LMt); }
    tr[s] = vr; ti[s] = vi;
  }
  U4CLASS(0) U4CLASS(1) U4CLASS(2) U4CLASS(3)
  #pragma unroll
  for (int s = 0; s < 16; ++s) {
    float br = tr[s ^ SMc], bi = ti[s ^ SMc];
    if constexpr (LMc != 0) { br = __shfl_xor(br, LMc); bi = __shfl_xor(bi, LMc); }
    pr[s] += br; pi[s] += bi;
  }
}

// ---- U3 coefficient build -------------------------------------------------
DEV void u3_make(float t, float p, float l, float* u) {
  float c = __cosf(0.5f * t), s = __sinf(0.5f * t);
  float cp = __cosf(p), sp = __sinf(p);
  float cl = __cosf(l), sl = __sinf(l);
  float cpl = __cosf(p + l), spl = __sinf(p + l);
  u[0] = c;        u[1] = 0.0f;
  u[2] = -cl * s;  u[3] = -sl * s;
  u[4] = cp * s;   u[5] = sp * s;
  u[6] = cpl * c;  u[7] = spl * c;
}

// ---- <Z3>,<Z7>: r3 = (LR=10,SR=1), r7 = (LR=10,SR=0) ----------------------
DEV void expz_fin(const float* pr, const float* pi, int lane, float& z3, float& z7) {
  float t3 = 0.0f, t7 = 0.0f;
  #pragma unroll
  for (int s = 0; s < 16; ++s) {
    float p = pr[s] * pr[s] + pi[s] * pi[s];
    t7 += p;
    t3 += (s & 1) ? -p : p;
  }
  if (lpar(lane, 10)) { t3 = -t3; t7 = -t7; }
  #pragma unroll
  for (int m = 1; m < 16; m <<= 1) {
    t3 += __shfl_xor(t3, m);
    t7 += __shfl_xor(t7, m);
  }
  z3 = t3; z7 = t7;
}

// ---------------------------------------------------------------------------

__global__ __launch_bounds__(256, 2)
void qcnn_kernel(const float* __restrict__ x,
                 const float* __restrict__ rz_p, const float* __restrict__ ry_p,
                 const float* __restrict__ ry2_p, const float* __restrict__ crx_p,
                 const float* __restrict__ u3_p, const float* __restrict__ u3b_p,
                 const float* __restrict__ W1, const float* __restrict__ b1,
                 const float* __restrict__ W2, const float* __restrict__ b2,
                 float* __restrict__ out, int B) {
  __shared__ __align__(8) float cw[64];       // 2 layers x 16 complex fused-U4
  __shared__ float4 encs[256][5];             // enc parked (stride 20 floats)

  const int tid  = threadIdx.x;
  const int lane = tid & 63;
  const int wave = tid >> 6;
  const int grp  = lane >> 4;
  const int sub  = lane & 15;
  const int gb   = lane & 48;
  const int elem = blockIdx.x * 16 + wave * 4 + grp;
  const int elemc = elem < B ? elem : (B - 1);

  // ---- fused U4 build (wave 0, lanes 0..31; one complex entry per lane) ---
  if (tid < 32) {
    const int lay = tid >> 4, e = tid & 15, i4 = e >> 2, j4 = e & 3;
    const int base = tid & 48;
    const float c45 = 0.70710678118654752f;
    float rz = rz_p[lay], ry = ry_p[lay], ry2 = ry2_p[lay];
    float mr = (i4 == j4) ? c45 : 0.0f;
    float mi = (i4 == j4) ? ((i4 & 1) ? -c45 : c45) : 0.0f;
    { int t = (i4 & 1) ? (i4 ^ 2) : i4; int src = base | (t << 2) | j4;
      mr = __shfl(mr, src); mi = __shfl(mi, src); }
    { float cz = __cosf(0.5f * rz), sz = __sinf(0.5f * rz);
      float di = (i4 & 2) ? sz : -sz;
      float nr = cz * mr - di * mi, ni = cz * mi + di * mr; mr = nr; mi = ni; }
    { float cy = __cosf(0.5f * ry), sy = __sinf(0.5f * ry);
      int src = base | ((i4 ^ 1) << 2) | j4;
      float orr = __shfl(mr, src), oii = __shfl(mi, src);
      float sg = (i4 & 1) ? sy : -sy;
      mr = cy * mr + sg * orr; mi = cy * mi + sg * oii; }
    { int t = (i4 & 2) ? (i4 ^ 1) : i4; int src = base | (t << 2) | j4;
      mr = __shfl(mr, src); mi = __shfl(mi, src); }
    { float cy = __cosf(0.5f * ry2), sy = __sinf(0.5f * ry2);
      int src = base | ((i4 ^ 1) << 2) | j4;
      float orr = __shfl(mr, src), oii = __shfl(mi, src);
      float sg = (i4 & 1) ? sy : -sy;
      mr = cy * mr + sg * orr; mi = cy * mi + sg * oii; }
    { int t = (i4 & 1) ? (i4 ^ 2) : i4; int src = base | (t << 2) | j4;
      mr = __shfl(mr, src); mi = __shfl(mi, src); }
    { float di = (i4 & 2) ? c45 : -c45;
      float nr = c45 * mr - di * mi, ni = c45 * mi + di * mr; mr = nr; mi = ni; }
    cw[(lay * 16 + e) * 2]     = mr;
    cw[(lay * 16 + e) * 2 + 1] = mi;
  }

  // ---- angles: lane sub holds angles 2*sub, 2*sub+1 -----------------------
  float2 aa = ((const float2*)x)[(size_t)elemc * 16 + sub];
  float ch0 = __cosf(0.5f * aa.x), sh0 = __sinf(0.5f * aa.x);
  float ch1 = __cosf(0.5f * aa.y), sh1 = __sinf(0.5f * aa.y);

  float cq[8], sq[8];
  #pragma unroll
  for (int q = 0; q < 8; ++q) {
    cq[q] = __shfl((q & 1) ? ch1 : ch0, gb | (q >> 1));
    sq[q] = __shfl((q & 1) ? sh1 : sh0, gb | (q >> 1));
  }

  // ---- product-state init (replaces cycle-1 RYs; state real) --------------
  float p[16];
  {
    float g = ((sub & 8) ? sq[0] : cq[0]) * ((sub & 4) ? sq[2] : cq[2]) *
              ((sub & 2) ? sq[4] : cq[4]) * ((sub & 1) ? sq[6] : cq[6]);
    float h13[4] = {cq[1]*cq[3], cq[1]*sq[3], sq[1]*cq[3], sq[1]*sq[3]};
    float h57[4] = {cq[5]*cq[7], cq[5]*sq[7], sq[5]*cq[7], sq[5]*sq[7]};
    #pragma unroll
    for (int i = 0; i < 4; ++i) h13[i] *= g;
    #pragma unroll
    for (int s = 0; s < 16; ++s) p[s] = h13[s >> 2] * h57[s & 3];
  }

  // ---- encode cycles 2..4 (24 real RYs, CNOTs folded into masks) ----------
  #define ENC(k, LM, SM, LR, SR) {                                  \
    float gc = __shfl(((k) & 1) ? ch1 : ch0, gb | ((k) >> 1));      \
    float gs = __shfl(((k) & 1) ? sh1 : sh0, gb | ((k) >> 1));      \
    ryr<LM, SM, LR, SR>(p, gc, gs, lane); }

  ENC(8,  8,8, 7,15)  ENC(9,  4,8, 8,8)   ENC(10, 4,4, 12,8)  ENC(11, 2,4, 12,12)
  ENC(12, 2,2, 14,12) ENC(13, 1,2, 14,14) ENC(14, 1,1, 15,14) ENC(15, 8,9, 15,15)
  ENC(16, 12,0, 8,15) ENC(17, 0,12, 15,7) ENC(18, 6,0, 3,15)  ENC(19, 0,6, 15,3)
  ENC(20, 3,0, 1,15)  ENC(21, 0,3, 15,1)  ENC(22, 9,8, 0,15)  ENC(23, 4,9, 15,0)
  ENC(24, 12,12, 2,10) ENC(25, 6,12, 7,8) ENC(26, 6,6, 4,7)   ENC(27, 3,6, 11,4)
  ENC(28, 3,3, 10,11)  ENC(29, 9,11, 5,10) ENC(30, 13,1, 5,5) ENC(31, 8,5, 10,5)
  #undef ENC

  // ---- park real encode state in LDS for psi1 -----------------------------
  #pragma unroll
  for (int k = 0; k < 4; ++k)
    encs[tid][k] = make_float4(p[4*k], p[4*k+1], p[4*k+2], p[4*k+3]);

  __syncthreads();  // cw ready
  const float2* w0 = (const float2*)cw;
  const float2* w1 = ((const float2*)cw) + 16;

  // ---- psi0: conv layers --------------------------------------------------
  float pi_[16];
  #pragma unroll
  for (int s = 0; s < 16; ++s) pi_[s] = 0.0f;

  u4_g<10,0,  0,10, 8,10, 5,2 >(p, pi_, w0, lane);   // (0,1)
  u4_g<5,0,   0,5,  1,5,  10,1>(p, pi_, w0, lane);   // (2,3)
  u4_g<10,8,  4,10, 0,10, 5,0 >(p, pi_, w0, lane);   // (4,5)
  u4_g<5,4,   2,5,  0,5,  10,0>(p, pi_, w0, lane);   // (6,7)
  u4_g<0,10,  5,0,  5,2,  1,5 >(p, pi_, w0, lane);   // (1,2)
  u4_g<0,5,   10,8, 10,1, 0,10>(p, pi_, w0, lane);   // (3,4)
  u4_g<4,10,  5,4,  5,0,  0,5 >(p, pi_, w0, lane);   // (5,6)
  {
    float ua[8]; u3_make(u3_p[0], u3_p[1], u3_p[2], ua);
    u3_g<0,10, 5,2 >(p, pi_, ua, lane);   // q1
    u3_g<0,5,  10,1>(p, pi_, ua, lane);   // q3
    u3_g<4,10, 5,0 >(p, pi_, ua, lane);   // q5
    u3_g<2,5,  10,0>(p, pi_, ua, lane);   // q7
  }
  u4_g<0,10,  0,5,  5,2,  10,1>(p, pi_, w1, lane);   // (1,3)
  u4_g<4,10,  2,5,  5,0,  10,0>(p, pi_, w1, lane);   // (5,7)
  u4_g<0,5,   4,10, 10,1, 5,0 >(p, pi_, w1, lane);   // (3,5)
  {
    float ua[8]; u3_make(u3_p[3], u3_p[4], u3_p[5], ua);
    u3_g<0,5,  10,1>(p, pi_, ua, lane);   // q3
    u3_g<2,5,  10,0>(p, pi_, ua, lane);   // q7
  }

  float f0, f1;
  expz_fin(p, pi_, lane, f0, f1);

  // ---- psi1: restore enc from LDS, CRX ladders + U3b ----------------------
  #pragma unroll
  for (int k = 0; k < 4; ++k) {
    float4 v = encs[tid][k];
    p[4*k] = v.x; p[4*k+1] = v.y; p[4*k+2] = v.z; p[4*k+3] = v.w;
    pi_[4*k] = 0.0f; pi_[4*k+1] = 0.0f; pi_[4*k+2] = 0.0f; pi_[4*k+3] = 0.0f;
  }

  {
    float t = crx_p[0];
    float cc = __cosf(0.5f * t), ss = __sinf(0.5f * t);
    crx_g<0,10, 8,10>(p, pi_, cc, ss, lane);   // (0,1)
    crx_g<0,5,  1,5 >(p, pi_, cc, ss, lane);   // (2,3)
    crx_g<4,10, 0,10>(p, pi_, cc, ss, lane);   // (4,5)
    crx_g<2,5,  0,5 >(p, pi_, cc, ss, lane);   // (6,7)
    crx_g<5,0,  5,2 >(p, pi_, cc, ss, lane);   // (1,2)
    crx_g<10,8, 10,1>(p, pi_, cc, ss, lane);   // (3,4)
    crx_g<5,4,  5,0 >(p, pi_, cc, ss, lane);   // (5,6)
  }
  {
    float ub[8]; u3_make(u3b_p[0], u3b_p[1], u3b_p[2], ub);
    u3_g<0,10, 5,2 >(p, pi_, ub, lane);
    u3_g<0,5,  10,1>(p, pi_, ub, lane);
    u3_g<4,10, 5,0 >(p, pi_, ub, lane);
    u3_g<2,5,  10,0>(p, pi_, ub, lane);
  }
  {
    float t = crx_p[1];
    float cc = __cosf(0.5f * t), ss = __sinf(0.5f * t);
    crx_g<0,5,  5,2 >(p, pi_, cc, ss, lane);   // (1,3)
    crx_g<2,5,  5,0 >(p, pi_, cc, ss, lane);   // (5,7)
    crx_g<4,10, 10,1>(p, pi_, cc, ss, lane);   // (3,5)
  }
  {
    float ub[8]; u3_make(u3b_p[3], u3b_p[4], u3b_p[5], ub);
    u3_g<0,5,  10,1>(p, pi_, ub, lane);
    u3_g<2,5,  10,0>(p, pi_, ub, lane);
  }

  float f2, f3;
  expz_fin(p, pi_, lane, f2, f3);

  // ---- MLP ----------------------------------------------------------------
  const int j = (sub < 15) ? sub : 0;
  float acc = W1[j * 4 + 0] * f0 + W1[j * 4 + 1] * f1 +
              W1[j * 4 + 2] * f2 + W1[j * 4 + 3] * f3 + b1[j];
  float e2 = __expf(2.0f * acc);
  float th = (e2 - 1.0f) / (e2 + 1.0f);
  float part = (sub < 15) ? th * W2[j] : 0.0f;
  #pragma unroll
  for (int m = 1; m < 16; m <<= 1) part += __shfl_xor(part, m);

  if (sub == 0 && elem < B) {
    float z = part + b2[0];
    out[elem] = 1.0f / (1.0f + __expf(-z));
  }
}

extern "C" void kernel_launch(void* const* d_in, const int* in_sizes, int n_in,
                              void* d_out, int out_size, void* d_ws, size_t ws_size,
                              hipStream_t stream) {
  (void)n_in; (void)out_size; (void)d_ws; (void)ws_size;
  const float* x     = (const float*)d_in[0];
  const float* rz_p  = (const float*)d_in[1];
  const float* ry_p  = (const float*)d_in[2];
  const float* ry2_p = (const float*)d_in[3];
  const float* crx_p = (const float*)d_in[4];
  const float* u3_p  = (const float*)d_in[5];
  const float* u3b_p = (const float*)d_in[6];
  const float* W1    = (const float*)d_in[7];
  const float* b1    = (const float*)d_in[8];
  const float* W2    = (const float*)d_in[9];
  const float* b2    = (const float*)d_in[10];
  float* out = (float*)d_out;

  const int B = in_sizes[0] / 32;          // 8192
  const int blocks = (B + 15) / 16;        // 4 elems/wave, 4 waves/block
  qcnn_kernel<<<dim3(blocks), dim3(256), 0, stream>>>(
      x, rz_p, ry_p, ry2_p, crx_p, u3_p, u3b_p, W1, b1, W2, b2, out, B);
}